// Round 12
// baseline (148.279 us; speedup 1.0000x reference)
//
#include <hip/hip_runtime.h>

// GraphConv (DGL norm='both', implicit self-loop), N=100000, D=64, E=1250000.
// R18 (2nd resubmit — rounds 10 & 11 hit GPUAcquisitionTimeout, never run).
// LDS-op halving via atomic-return ranks. R17 post-mortem: partition
// ~31us residual with VALUBusy 1.3% and only ~25MB traffic; arithmetic says
// 16K LDS atomic insts/block (hist 8K + scatter-cursor 8K) at ~2.5-4cy eff
// = 20-30us — the LDS pipe is the floor. Same pattern in sortgather's sort
// phase (5M LDS ops for 1.25M edges: stage-write/hist/re-read/scatter).
// Fix (both kernels): the hist atomicAdd ALREADY returns the edge's rank in
// (block,bin) — keep it in registers; scatter pos = base[bin]+rank. Kills
// lcurA/lcurB (8192 atomics/block) in partition; kills sAl (12KB LDS),
// 1.25M stage-writes, 1.25M re-reads, 1.25M scatter atomics in sortgather
// (staged values live in vv[3]/rk[3] VGPRs, statically indexed).
// Position sets per (block,bin) unchanged — only intra-block order differs.
// No new vector-memory patterns (R16-crash-safe).
// Predicted: partition ~31->22-25, total 147.8 -> ~135-141.
// Pre-committed: total unchanged => LDS-op rate not the floor; next round
// coalesce scatter stores via LDS-sorted runs.

#define GC_D 64
#define PSIZE 196     // nodes per partition: ceil(100000/511); 511 ~ 2*256 CUs
#define SCAP 3072     // stream slots per partition (mean 2450, +12 sigma)
#define EPT 8         // edges per thread (2x int4 per edge array)
#define EPB (512*EPT) // 4096 edges per block: 306 blocks
#define MAXPART 512
#define GC_CAP 64     // fallback-A bucket capacity

// ---------------- main-path kernels ----------------

__global__ __launch_bounds__(512) void partition_kernel(
        const int* __restrict__ src,
        const int* __restrict__ dst,
        int* __restrict__ curA,                 // [nPart] cursors (dst-keyed)
        int* __restrict__ curB,                 // [nPart] cursors (src-keyed)
        int* __restrict__ streamA,              // [nPart*SCAP] s | (d%PSIZE)<<17
        unsigned char* __restrict__ streamB,    // [nPart*SCAP] s%PSIZE
        int e, int nPart) {
    __shared__ int histA[MAXPART], histB[MAXPART], baseA[MAXPART], baseB[MAXPART];
    int t = threadIdx.x;
    for (int i = t; i < nPart; i += 512) { histA[i] = 0; histB[i] = 0; }
    __syncthreads();
    int base_i = blockIdx.x * EPB + t * EPT;
    int se[EPT], de[EPT], rkA[EPT], rkB[EPT];
    bool aligned16 = ((((size_t)src) | ((size_t)dst)) & 15) == 0;
    if (aligned16 && base_i + EPT <= e) {
        // fast path: 2x int4 per array (base_i multiple of 8 -> 32B offset)
        int4 s0 = *(const int4*)(src + base_i);
        int4 s1 = *(const int4*)(src + base_i + 4);
        int4 d0 = *(const int4*)(dst + base_i);
        int4 d1 = *(const int4*)(dst + base_i + 4);
        se[0]=s0.x; se[1]=s0.y; se[2]=s0.z; se[3]=s0.w;
        se[4]=s1.x; se[5]=s1.y; se[6]=s1.z; se[7]=s1.w;
        de[0]=d0.x; de[1]=d0.y; de[2]=d0.z; de[3]=d0.w;
        de[4]=d1.x; de[5]=d1.y; de[6]=d1.z; de[7]=d1.w;
#pragma unroll
        for (int k = 0; k < EPT; ++k) {
            rkA[k] = atomicAdd(&histA[de[k] / PSIZE], 1);   // rank in (block,bin)
            rkB[k] = atomicAdd(&histB[se[k] / PSIZE], 1);
        }
    } else {
#pragma unroll
        for (int k = 0; k < EPT; ++k) {
            int i = base_i + k;
            se[k] = 0; de[k] = 0; rkA[k] = 0; rkB[k] = 0;
            if (i < e) {
                se[k] = src[i]; de[k] = dst[i];
                rkA[k] = atomicAdd(&histA[de[k] / PSIZE], 1);
                rkB[k] = atomicAdd(&histB[se[k] / PSIZE], 1);
            }
        }
    }
    __syncthreads();
    for (int i = t; i < nPart; i += 512) {
        int hA = histA[i];
        baseA[i] = hA ? atomicAdd(&curA[i], hA) : 0;
        int hB = histB[i];
        baseB[i] = hB ? atomicAdd(&curB[i], hB) : 0;
    }
    __syncthreads();
#pragma unroll
    for (int k = 0; k < EPT; ++k) {
        int i = base_i + k;
        if (i < e) {
            int s = se[k], d = de[k];
            int pA = d / PSIZE;                  // compile-time magic div
            int posA = baseA[pA] + rkA[k];
            if (posA < SCAP) streamA[pA * SCAP + posA] = s | ((d - pA * PSIZE) << 17);
            int pB = s / PSIZE;
            int posB = baseB[pB] + rkB[k];
            if (posB < SCAP) streamB[pB * SCAP + posB] = (unsigned char)(s - pB * PSIZE);
        }
    }
}

__device__ __forceinline__ unsigned short to_bf16_rne(float v) {
    unsigned b = __float_as_uint(v);
    b = (b + 0x7FFFu + ((b >> 16) & 1u)) >> 16;   // RNE to bf16
    return (unsigned short)b;
}

// One block per partition: outdeg hist from streamB (256-bin LDS), then
// VECTORIZED premultiplied bf16 convert of this partition's PSIZE rows
// (float4 in / ushort4 out per lane). featb row n = zeros (pad target).
// (byte-exact R15/R17 version — proven)
__global__ __launch_bounds__(512) void convertB_kernel(
        const int* __restrict__ curB,
        const unsigned char* __restrict__ streamB,
        const float* __restrict__ feat,
        unsigned short* __restrict__ featb,
        int n) {
    __shared__ int lodeg[256];
    __shared__ float lnl[256];
    int p = blockIdx.x, t = threadIdx.x;
    if (t < 256) lodeg[t] = 0;
    __syncthreads();
    int cB = min(curB[p], SCAP);
    const unsigned char* sB = streamB + (size_t)p * SCAP;
    for (int i = t; i < cB; i += 512) atomicAdd(&lodeg[sB[i]], 1);
    __syncthreads();
    if (t < 256) lnl[t] = rsqrtf(fmaxf((float)lodeg[t], 1.0f) + 1.0f);
    __syncthreads();
    int g = p * PSIZE;
    // PSIZE*16 float4-quads per partition; q>>4 monotone in q so break is safe
    for (int q = t; q < PSIZE * 16; q += 512) {
        int r = q >> 4;
        int node = g + r;
        if (node >= n) break;
        float nl = lnl[r];
        size_t base = (size_t)node * GC_D + (q & 15) * 4;
        const float4 v = *(const float4*)(feat + base);
        ushort4 rr;
        rr.x = to_bf16_rne(v.x * nl);
        rr.y = to_bf16_rne(v.y * nl);
        rr.z = to_bf16_rne(v.z * nl);
        rr.w = to_bf16_rne(v.w * nl);
        *(ushort4*)(featb + base) = rr;
    }
    if (p == 0 && t < GC_D) featb[(size_t)n * GC_D + t] = 0;
}

// One 1024-thread block per partition. Stream entries held in VGPRs
// (vv[3]/rk[3], SCAP=3072=3*1024, statically indexed), rank from the hist
// atomic's return value -> counting sort writes lperm directly. sAl and the
// scatter-cursor atomics are gone. Gather phase = R9-proven pattern.
__global__ __launch_bounds__(1024) void sortgather_kernel(
        const int* __restrict__ curA,
        const int* __restrict__ streamA,
        const float* __restrict__ feat,
        const unsigned short* __restrict__ featb,
        float* __restrict__ out,
        int n) {
    __shared__ int lperm[SCAP];     // 12 KB sorted src ids
    __shared__ int lcnt[256], loff[256];
    int p = blockIdx.x, t = threadIdx.x;
    if (t < 256) lcnt[t] = 0;
    __syncthreads();
    int cA = min(curA[p], SCAP);
    const int* sA = streamA + (size_t)p * SCAP;
    int vv[3], rk[3];               // SCAP/1024 == 3 iterations, static idx
#pragma unroll
    for (int it = 0; it < 3; ++it) {
        int i = it * 1024 + t;
        vv[it] = 0; rk[it] = -1;
        if (i < cA) {
            int v = sA[i];
            vv[it] = v;
            rk[it] = atomicAdd(&lcnt[(v >> 17) & 255], 1);   // rank in bin
        }
    }
    __syncthreads();
    // exclusive scan of 256 bins (Hillis-Steele on first 256 threads)
    if (t < 256) loff[t] = lcnt[t];
    __syncthreads();
    for (int off = 1; off < 256; off <<= 1) {
        int a = (t < 256 && t >= off) ? loff[t - off] : 0;
        __syncthreads();
        if (t < 256) loff[t] += a;
        __syncthreads();
    }
    if (t < 256) loff[t] -= lcnt[t];    // exclusive
    __syncthreads();
#pragma unroll
    for (int it = 0; it < 3; ++it) {
        if (rk[it] >= 0) {
            int v = vv[it];
            lperm[loff[(v >> 17) & 255] + rk[it]] = v & 0x1FFFF;
        }
    }
    __syncthreads();
    // gather: wave w handles nodes w, w+16, ...
    int wave = t >> 6, lane = t & 63;
    int half = lane >> 5;      // 0: even edges, 1: odd edges
    int c = lane & 31;         // feature-pair index
    int g = p * PSIZE;
    for (int r = wave; r < PSIZE; r += 16) {
        int node = g + r;
        if (node >= n) break;
        int deg = lcnt[r];
        int off = loff[r];
        float acc0 = 0.0f, acc1 = 0.0f;
        for (int base = 0; base < deg; base += 64) {
            int m = min(deg - base, 64);
            int s_l = (lane < m) ? lperm[off + base + lane] : n;
            int m16 = (m + 15) & ~15;
            for (int j = 0; j < m16; j += 16) {
#pragma unroll
                for (int k = 0; k < 8; ++k) {
                    int s = __shfl(s_l, j + 2 * k + half);
                    unsigned u = *(const unsigned*)(featb + (size_t)s * GC_D + 2 * c);
                    acc0 += __uint_as_float(u << 16);
                    acc1 += __uint_as_float(u & 0xFFFF0000u);
                }
            }
        }
        acc0 += __shfl_xor(acc0, 32);
        acc1 += __shfl_xor(acc1, 32);
        if (half == 0) {
            float nr = rsqrtf(fmaxf((float)deg, 1.0f) + 1.0f);
            const float2 self = *(const float2*)(feat + (size_t)node * GC_D + 2 * c);
            float2 rr;
            rr.x = (self.x + acc0) * nr;
            rr.y = (self.y + acc1) * nr;
            *(float2*)(out + (size_t)node * GC_D + 2 * c) = rr;
        }
    }
}

// ---------------- fallback A (atomic-bucket path, R4-style) ----------------

__global__ void zero_int_kernel(int* __restrict__ p, int n) {
    int i = blockIdx.x * blockDim.x + threadIdx.x;
    if (i < n) p[i] = 0;
}

__global__ void bucket_hist_kernel(const int* __restrict__ src,
                                   const int* __restrict__ dst,
                                   int* __restrict__ cnt,
                                   int* __restrict__ outdeg,
                                   int* __restrict__ bucket,
                                   int e) {
    int i = blockIdx.x * blockDim.x + threadIdx.x;
    if (i < e) {
        int s = src[i];
        int d = dst[i];
        atomicAdd(&outdeg[s], 1);
        int pos = atomicAdd(&cnt[d], 1);
        if (pos < GC_CAP) bucket[d * GC_CAP + pos] = s;
    }
}

__global__ __launch_bounds__(256) void convert_kernel(
        const float* __restrict__ feat,
        const int* __restrict__ outdeg,
        unsigned short* __restrict__ featb,
        int n) {
    int i = blockIdx.x * 256 + threadIdx.x;   // float4 / ushort4 index
    int row = i >> 4;
    if (row > n) return;
    if (row == n) {
        ushort4 z; z.x = 0; z.y = 0; z.z = 0; z.w = 0;
        *(ushort4*)(featb + (size_t)i * 4) = z;
        return;
    }
    float nl = rsqrtf(fmaxf((float)outdeg[row], 1.0f) + 1.0f);
    float4 v = *(const float4*)(feat + (size_t)i * 4);
    ushort4 r;
    r.x = to_bf16_rne(v.x * nl);
    r.y = to_bf16_rne(v.y * nl);
    r.z = to_bf16_rne(v.z * nl);
    r.w = to_bf16_rne(v.w * nl);
    *(ushort4*)(featb + (size_t)i * 4) = r;
}

__global__ __launch_bounds__(256) void gather_bf16_kernel(
        const float* __restrict__ feat,
        const unsigned short* __restrict__ featb,
        const int* __restrict__ bucket,
        const int* __restrict__ cnt,
        float* __restrict__ out,
        int n) {
    int wid = (blockIdx.x * blockDim.x + threadIdx.x) >> 6;
    int lane = threadIdx.x & 63;
    if (wid >= n) return;
    int deg = cnt[wid];
    int s_raw = bucket[wid * GC_CAP + lane];
    int m = min(deg, GC_CAP);
    int s_l = (lane < m) ? s_raw : n;
    int half = lane >> 5;
    int c = lane & 31;
    float acc0 = 0.0f, acc1 = 0.0f;
    int m16 = (m + 15) & ~15;
    for (int j = 0; j < m16; j += 16) {
#pragma unroll
        for (int k = 0; k < 8; ++k) {
            int s = __shfl(s_l, j + 2 * k + half);
            unsigned u = *(const unsigned*)(featb + (size_t)s * GC_D + 2 * c);
            acc0 += __uint_as_float(u << 16);
            acc1 += __uint_as_float(u & 0xFFFF0000u);
        }
    }
    acc0 += __shfl_xor(acc0, 32);
    acc1 += __shfl_xor(acc1, 32);
    if (half == 0) {
        float nr = rsqrtf(fmaxf((float)deg, 1.0f) + 1.0f);
        const float2 self = *(const float2*)(feat + (size_t)wid * GC_D + 2 * c);
        float2 r;
        r.x = (self.x + acc0) * nr;
        r.y = (self.y + acc1) * nr;
        *(float2*)(out + (size_t)wid * GC_D + 2 * c) = r;
    }
}

// ---------------- launch ----------------

extern "C" void kernel_launch(void* const* d_in, const int* in_sizes, int n_in,
                              void* d_out, int out_size, void* d_ws, size_t ws_size,
                              hipStream_t stream) {
    const float* feat = (const float*)d_in[0];
    const int*   src  = (const int*)d_in[1];
    const int*   dst  = (const int*)d_in[2];
    float* out = (float*)d_out;

    const int n = in_sizes[0] / GC_D;   // 100000
    const int e = in_sizes[1];          // 1250000
    const int nPart = (n + PSIZE - 1) / PSIZE;    // 511 for n=100000

    // Main ws layout (int units): curA[nPart] curB[nPart] pad32 ->
    //   streamA[nPart*SCAP] -> featb[(n+1)*64 u16] -> streamB[nPart*SCAP u8]
    size_t featb_ints = ((size_t)(n + 1) * GC_D + 1) / 2;
    size_t o = 2 * (size_t)nPart;
    o = (o + 31) & ~(size_t)31;          // 128B-align streamA (and featb below)
    size_t streamA_o = o;  o += (size_t)nPart * SCAP;
    size_t featb_o = o;    o += featb_ints;
    size_t need_main = o * sizeof(int) + (size_t)nPart * SCAP;   // + streamB u8

    size_t featb_bytes = (size_t)(n + 1) * GC_D * sizeof(unsigned short);
    size_t need_bf16 = ((size_t)2 * n + (size_t)n * GC_CAP) * sizeof(int) + featb_bytes;

    bool main_ok = (ws_size >= need_main) && nPart <= MAXPART && n <= 131071;

    if (main_ok) {
        int* ws = (int*)d_ws;
        int* curA = ws;
        int* curB = ws + nPart;
        int* streamA = ws + streamA_o;
        unsigned short* featb = (unsigned short*)(ws + featb_o);
        unsigned char* streamB = (unsigned char*)(ws + o);

        hipMemsetAsync(curA, 0, 2 * (size_t)nPart * sizeof(int), stream);
        partition_kernel<<<(e + EPB - 1) / EPB, 512, 0, stream>>>(
            src, dst, curA, curB, streamA, streamB, e, nPart);
        convertB_kernel<<<nPart, 512, 0, stream>>>(curB, streamB, feat, featb, n);
        sortgather_kernel<<<nPart, 1024, 0, stream>>>(curA, streamA, feat, featb,
                                                      out, n);
    } else if (ws_size >= need_bf16) {
        int* cnt    = (int*)d_ws;
        int* outdeg = cnt + n;
        int* bucket = outdeg + n;
        unsigned short* featb = (unsigned short*)(bucket + (size_t)n * GC_CAP);

        zero_int_kernel<<<(2 * n + 255) / 256, 256, 0, stream>>>(cnt, 2 * n);
        bucket_hist_kernel<<<(e + 255) / 256, 256, 0, stream>>>(src, dst, cnt,
                                                                outdeg, bucket, e);
        int conv_threads = (n + 1) * 16;
        convert_kernel<<<(conv_threads + 255) / 256, 256, 0, stream>>>(
            feat, outdeg, featb, n);
        long long total = (long long)n * GC_D;
        gather_bf16_kernel<<<(int)((total + 255) / 256), 256, 0, stream>>>(
            feat, featb, bucket, cnt, out, n);
    }
}

// Round 15
// 139.807 us; speedup vs baseline: 1.0606x; 1.0606x over previous
//
#include <hip/hip_runtime.h>

// GraphConv (DGL norm='both', implicit self-loop), N=100000, D=64, E=1250000.
// R19 (2nd resubmit — rounds 13 & 14 hit GPUAcquisitionTimeout, never run).
// Partition balance + coalesced stream writes. Ledger: partition ~31us
// is NOT load latency (R17 fixed, -8), NOT LDS-atomic rate (R18: 0), NOT
// grid size per se (R13/14: ~1us). Remaining by arithmetic:
//  (a) 306 blocks on 256 CUs -> 50 CUs run 2 sequential blocks: total =
//      2 x block_time. EPT 8->12 (3x int4, 48B-aligned) => EPB 6144 =>
//      204 blocks <= 256: imbalance tail gone, total = 1 x block_time.
//  (b) streamA scatter = ~12 separate 4B stores per (block,bin) run, no
//      coalescing (R13 measured ~8x write amp). Fix: block-level exclusive
//      scan of histA -> sorted LDS staging (sval/sbin, 36KB) -> linear
//      sweep writes runs with consecutive lanes = consecutive addresses.
//  B-side byte stream stays direct (1.25MB payload, amp immaterial).
// convertB/sortgather: byte-exact R18 (measured 148.3, passed).
// Predicted: partition ~31 -> 18-22, total 148.3 -> ~136-141.
// Pre-committed: dTotal < 4us => partition floor is hist/barrier structure
// => next round: feature-sliced gather (8 slabs x 1.6MB, L2-resident/XCD)
// targeting sortgather's ~40us L3-bound random reads. Known risk: the
// MAXPART-wide scan adds 18 barriers — if partition REGRESSES, that's it.

#define GC_D 64
#define PSIZE 196     // nodes per partition: ceil(100000/511); 511 ~ 2*256 CUs
#define SCAP 3072     // stream slots per partition (mean 2450, +12 sigma)
#define EPT 12        // edges per thread (3x int4 per edge array; 48B align)
#define EPB (512*EPT) // 6144 edges per block: 204 blocks (<= 256 CUs)
#define MAXPART 512
#define GC_CAP 64     // fallback-A bucket capacity

// ---------------- main-path kernels ----------------

__global__ __launch_bounds__(512) void partition_kernel(
        const int* __restrict__ src,
        const int* __restrict__ dst,
        int* __restrict__ curA,                 // [nPart] cursors (dst-keyed)
        int* __restrict__ curB,                 // [nPart] cursors (src-keyed)
        int* __restrict__ streamA,              // [nPart*SCAP] s | (d%PSIZE)<<17
        unsigned char* __restrict__ streamB,    // [nPart*SCAP] s%PSIZE
        int e, int nPart) {
    __shared__ int histA[MAXPART], histB[MAXPART], baseA[MAXPART], baseB[MAXPART];
    __shared__ int lofsA[MAXPART];              // inclusive scan of histA
    __shared__ int sval[EPB];                   // 24 KB sorted stream values
    __shared__ unsigned short sbin[EPB];        // 12 KB bin id per sorted slot
    int t = threadIdx.x;
    for (int i = t; i < nPart; i += 512) { histA[i] = 0; histB[i] = 0; }
    __syncthreads();
    int lo = blockIdx.x * EPB;
    int base_i = lo + t * EPT;
    int se[EPT], de[EPT], rkA[EPT], rkB[EPT];
    bool aligned16 = ((((size_t)src) | ((size_t)dst)) & 15) == 0;
    if (aligned16 && base_i + EPT <= e) {
        // fast path: 3x int4 per array (t*12 ints = 48B -> 16B-aligned)
        int4 s0 = *(const int4*)(src + base_i);
        int4 s1 = *(const int4*)(src + base_i + 4);
        int4 s2 = *(const int4*)(src + base_i + 8);
        int4 d0 = *(const int4*)(dst + base_i);
        int4 d1 = *(const int4*)(dst + base_i + 4);
        int4 d2 = *(const int4*)(dst + base_i + 8);
        se[0]=s0.x; se[1]=s0.y; se[2]=s0.z; se[3]=s0.w;
        se[4]=s1.x; se[5]=s1.y; se[6]=s1.z; se[7]=s1.w;
        se[8]=s2.x; se[9]=s2.y; se[10]=s2.z; se[11]=s2.w;
        de[0]=d0.x; de[1]=d0.y; de[2]=d0.z; de[3]=d0.w;
        de[4]=d1.x; de[5]=d1.y; de[6]=d1.z; de[7]=d1.w;
        de[8]=d2.x; de[9]=d2.y; de[10]=d2.z; de[11]=d2.w;
#pragma unroll
        for (int k = 0; k < EPT; ++k) {
            rkA[k] = atomicAdd(&histA[de[k] / PSIZE], 1);   // rank in (block,bin)
            rkB[k] = atomicAdd(&histB[se[k] / PSIZE], 1);
        }
    } else {
#pragma unroll
        for (int k = 0; k < EPT; ++k) {
            int i = base_i + k;
            se[k] = 0; de[k] = 0; rkA[k] = 0; rkB[k] = 0;
            if (i < e) {
                se[k] = src[i]; de[k] = dst[i];
                rkA[k] = atomicAdd(&histA[de[k] / PSIZE], 1);
                rkB[k] = atomicAdd(&histB[se[k] / PSIZE], 1);
            }
        }
    }
    __syncthreads();
    // global cursor reservation (histA/histB now hold block-local counts)
    for (int i = t; i < nPart; i += 512) {
        int hA = histA[i];
        baseA[i] = hA ? atomicAdd(&curA[i], hA) : 0;
        int hB = histB[i];
        baseB[i] = hB ? atomicAdd(&curB[i], hB) : 0;
    }
    // block-level inclusive scan of histA over MAXPART slots (512 threads)
    lofsA[t] = (t < nPart) ? histA[t] : 0;
    __syncthreads();
    for (int off = 1; off < MAXPART; off <<= 1) {
        int a = (t >= off) ? lofsA[t - off] : 0;
        __syncthreads();
        lofsA[t] += a;
        __syncthreads();
    }
    // scatter-in: sorted LDS slot = exclusive(lofsA) + rank; B-side direct
#pragma unroll
    for (int k = 0; k < EPT; ++k) {
        int i = base_i + k;
        if (i < e) {
            int s = se[k], d = de[k];
            int pA = d / PSIZE;                  // compile-time magic div
            int slot = lofsA[pA] - histA[pA] + rkA[k];
            sval[slot] = s | ((d - pA * PSIZE) << 17);
            sbin[slot] = (unsigned short)pA;
            int pB = s / PSIZE;
            int posB = baseB[pB] + rkB[k];
            if (posB < SCAP) streamB[pB * SCAP + posB] = (unsigned char)(s - pB * PSIZE);
        }
    }
    __syncthreads();
    // coalesced sweep: consecutive slots in a bin -> consecutive global addrs
    int nE = min(EPB, e - lo);
    for (int i = t; i < nE; i += 512) {
        int bin = sbin[i];
        int pos = baseA[bin] + (i - (lofsA[bin] - histA[bin]));
        if (pos < SCAP) streamA[bin * SCAP + pos] = sval[i];
    }
}

__device__ __forceinline__ unsigned short to_bf16_rne(float v) {
    unsigned b = __float_as_uint(v);
    b = (b + 0x7FFFu + ((b >> 16) & 1u)) >> 16;   // RNE to bf16
    return (unsigned short)b;
}

// One block per partition: outdeg hist from streamB (256-bin LDS), then
// VECTORIZED premultiplied bf16 convert of this partition's PSIZE rows
// (float4 in / ushort4 out per lane). featb row n = zeros (pad target).
// (byte-exact R18 version — proven)
__global__ __launch_bounds__(512) void convertB_kernel(
        const int* __restrict__ curB,
        const unsigned char* __restrict__ streamB,
        const float* __restrict__ feat,
        unsigned short* __restrict__ featb,
        int n) {
    __shared__ int lodeg[256];
    __shared__ float lnl[256];
    int p = blockIdx.x, t = threadIdx.x;
    if (t < 256) lodeg[t] = 0;
    __syncthreads();
    int cB = min(curB[p], SCAP);
    const unsigned char* sB = streamB + (size_t)p * SCAP;
    for (int i = t; i < cB; i += 512) atomicAdd(&lodeg[sB[i]], 1);
    __syncthreads();
    if (t < 256) lnl[t] = rsqrtf(fmaxf((float)lodeg[t], 1.0f) + 1.0f);
    __syncthreads();
    int g = p * PSIZE;
    // PSIZE*16 float4-quads per partition; q>>4 monotone in q so break is safe
    for (int q = t; q < PSIZE * 16; q += 512) {
        int r = q >> 4;
        int node = g + r;
        if (node >= n) break;
        float nl = lnl[r];
        size_t base = (size_t)node * GC_D + (q & 15) * 4;
        const float4 v = *(const float4*)(feat + base);
        ushort4 rr;
        rr.x = to_bf16_rne(v.x * nl);
        rr.y = to_bf16_rne(v.y * nl);
        rr.z = to_bf16_rne(v.z * nl);
        rr.w = to_bf16_rne(v.w * nl);
        *(ushort4*)(featb + base) = rr;
    }
    if (p == 0 && t < GC_D) featb[(size_t)n * GC_D + t] = 0;
}

// One 1024-thread block per partition. Stream entries held in VGPRs
// (vv[3]/rk[3], SCAP=3072=3*1024, statically indexed), rank from the hist
// atomic's return value -> counting sort writes lperm directly.
// (byte-exact R18 version — proven)
__global__ __launch_bounds__(1024) void sortgather_kernel(
        const int* __restrict__ curA,
        const int* __restrict__ streamA,
        const float* __restrict__ feat,
        const unsigned short* __restrict__ featb,
        float* __restrict__ out,
        int n) {
    __shared__ int lperm[SCAP];     // 12 KB sorted src ids
    __shared__ int lcnt[256], loff[256];
    int p = blockIdx.x, t = threadIdx.x;
    if (t < 256) lcnt[t] = 0;
    __syncthreads();
    int cA = min(curA[p], SCAP);
    const int* sA = streamA + (size_t)p * SCAP;
    int vv[3], rk[3];               // SCAP/1024 == 3 iterations, static idx
#pragma unroll
    for (int it = 0; it < 3; ++it) {
        int i = it * 1024 + t;
        vv[it] = 0; rk[it] = -1;
        if (i < cA) {
            int v = sA[i];
            vv[it] = v;
            rk[it] = atomicAdd(&lcnt[(v >> 17) & 255], 1);   // rank in bin
        }
    }
    __syncthreads();
    // exclusive scan of 256 bins (Hillis-Steele on first 256 threads)
    if (t < 256) loff[t] = lcnt[t];
    __syncthreads();
    for (int off = 1; off < 256; off <<= 1) {
        int a = (t < 256 && t >= off) ? loff[t - off] : 0;
        __syncthreads();
        if (t < 256) loff[t] += a;
        __syncthreads();
    }
    if (t < 256) loff[t] -= lcnt[t];    // exclusive
    __syncthreads();
#pragma unroll
    for (int it = 0; it < 3; ++it) {
        if (rk[it] >= 0) {
            int v = vv[it];
            lperm[loff[(v >> 17) & 255] + rk[it]] = v & 0x1FFFF;
        }
    }
    __syncthreads();
    // gather: wave w handles nodes w, w+16, ...
    int wave = t >> 6, lane = t & 63;
    int half = lane >> 5;      // 0: even edges, 1: odd edges
    int c = lane & 31;         // feature-pair index
    int g = p * PSIZE;
    for (int r = wave; r < PSIZE; r += 16) {
        int node = g + r;
        if (node >= n) break;
        int deg = lcnt[r];
        int off = loff[r];
        float acc0 = 0.0f, acc1 = 0.0f;
        for (int base = 0; base < deg; base += 64) {
            int m = min(deg - base, 64);
            int s_l = (lane < m) ? lperm[off + base + lane] : n;
            int m16 = (m + 15) & ~15;
            for (int j = 0; j < m16; j += 16) {
#pragma unroll
                for (int k = 0; k < 8; ++k) {
                    int s = __shfl(s_l, j + 2 * k + half);
                    unsigned u = *(const unsigned*)(featb + (size_t)s * GC_D + 2 * c);
                    acc0 += __uint_as_float(u << 16);
                    acc1 += __uint_as_float(u & 0xFFFF0000u);
                }
            }
        }
        acc0 += __shfl_xor(acc0, 32);
        acc1 += __shfl_xor(acc1, 32);
        if (half == 0) {
            float nr = rsqrtf(fmaxf((float)deg, 1.0f) + 1.0f);
            const float2 self = *(const float2*)(feat + (size_t)node * GC_D + 2 * c);
            float2 rr;
            rr.x = (self.x + acc0) * nr;
            rr.y = (self.y + acc1) * nr;
            *(float2*)(out + (size_t)node * GC_D + 2 * c) = rr;
        }
    }
}

// ---------------- fallback A (atomic-bucket path, R4-style) ----------------

__global__ void zero_int_kernel(int* __restrict__ p, int n) {
    int i = blockIdx.x * blockDim.x + threadIdx.x;
    if (i < n) p[i] = 0;
}

__global__ void bucket_hist_kernel(const int* __restrict__ src,
                                   const int* __restrict__ dst,
                                   int* __restrict__ cnt,
                                   int* __restrict__ outdeg,
                                   int* __restrict__ bucket,
                                   int e) {
    int i = blockIdx.x * blockDim.x + threadIdx.x;
    if (i < e) {
        int s = src[i];
        int d = dst[i];
        atomicAdd(&outdeg[s], 1);
        int pos = atomicAdd(&cnt[d], 1);
        if (pos < GC_CAP) bucket[d * GC_CAP + pos] = s;
    }
}

__global__ __launch_bounds__(256) void convert_kernel(
        const float* __restrict__ feat,
        const int* __restrict__ outdeg,
        unsigned short* __restrict__ featb,
        int n) {
    int i = blockIdx.x * 256 + threadIdx.x;   // float4 / ushort4 index
    int row = i >> 4;
    if (row > n) return;
    if (row == n) {
        ushort4 z; z.x = 0; z.y = 0; z.z = 0; z.w = 0;
        *(ushort4*)(featb + (size_t)i * 4) = z;
        return;
    }
    float nl = rsqrtf(fmaxf((float)outdeg[row], 1.0f) + 1.0f);
    float4 v = *(const float4*)(feat + (size_t)i * 4);
    ushort4 r;
    r.x = to_bf16_rne(v.x * nl);
    r.y = to_bf16_rne(v.y * nl);
    r.z = to_bf16_rne(v.z * nl);
    r.w = to_bf16_rne(v.w * nl);
    *(ushort4*)(featb + (size_t)i * 4) = r;
}

__global__ __launch_bounds__(256) void gather_bf16_kernel(
        const float* __restrict__ feat,
        const unsigned short* __restrict__ featb,
        const int* __restrict__ bucket,
        const int* __restrict__ cnt,
        float* __restrict__ out,
        int n) {
    int wid = (blockIdx.x * blockDim.x + threadIdx.x) >> 6;
    int lane = threadIdx.x & 63;
    if (wid >= n) return;
    int deg = cnt[wid];
    int s_raw = bucket[wid * GC_CAP + lane];
    int m = min(deg, GC_CAP);
    int s_l = (lane < m) ? s_raw : n;
    int half = lane >> 5;
    int c = lane & 31;
    float acc0 = 0.0f, acc1 = 0.0f;
    int m16 = (m + 15) & ~15;
    for (int j = 0; j < m16; j += 16) {
#pragma unroll
        for (int k = 0; k < 8; ++k) {
            int s = __shfl(s_l, j + 2 * k + half);
            unsigned u = *(const unsigned*)(featb + (size_t)s * GC_D + 2 * c);
            acc0 += __uint_as_float(u << 16);
            acc1 += __uint_as_float(u & 0xFFFF0000u);
        }
    }
    acc0 += __shfl_xor(acc0, 32);
    acc1 += __shfl_xor(acc1, 32);
    if (half == 0) {
        float nr = rsqrtf(fmaxf((float)deg, 1.0f) + 1.0f);
        const float2 self = *(const float2*)(feat + (size_t)wid * GC_D + 2 * c);
        float2 r;
        r.x = (self.x + acc0) * nr;
        r.y = (self.y + acc1) * nr;
        *(float2*)(out + (size_t)wid * GC_D + 2 * c) = r;
    }
}

// ---------------- launch ----------------

extern "C" void kernel_launch(void* const* d_in, const int* in_sizes, int n_in,
                              void* d_out, int out_size, void* d_ws, size_t ws_size,
                              hipStream_t stream) {
    const float* feat = (const float*)d_in[0];
    const int*   src  = (const int*)d_in[1];
    const int*   dst  = (const int*)d_in[2];
    float* out = (float*)d_out;

    const int n = in_sizes[0] / GC_D;   // 100000
    const int e = in_sizes[1];          // 1250000
    const int nPart = (n + PSIZE - 1) / PSIZE;    // 511 for n=100000

    // Main ws layout (int units): curA[nPart] curB[nPart] pad32 ->
    //   streamA[nPart*SCAP] -> featb[(n+1)*64 u16] -> streamB[nPart*SCAP u8]
    size_t featb_ints = ((size_t)(n + 1) * GC_D + 1) / 2;
    size_t o = 2 * (size_t)nPart;
    o = (o + 31) & ~(size_t)31;          // 128B-align streamA (and featb below)
    size_t streamA_o = o;  o += (size_t)nPart * SCAP;
    size_t featb_o = o;    o += featb_ints;
    size_t need_main = o * sizeof(int) + (size_t)nPart * SCAP;   // + streamB u8

    size_t featb_bytes = (size_t)(n + 1) * GC_D * sizeof(unsigned short);
    size_t need_bf16 = ((size_t)2 * n + (size_t)n * GC_CAP) * sizeof(int) + featb_bytes;

    bool main_ok = (ws_size >= need_main) && nPart <= MAXPART && n <= 131071;

    if (main_ok) {
        int* ws = (int*)d_ws;
        int* curA = ws;
        int* curB = ws + nPart;
        int* streamA = ws + streamA_o;
        unsigned short* featb = (unsigned short*)(ws + featb_o);
        unsigned char* streamB = (unsigned char*)(ws + o);

        hipMemsetAsync(curA, 0, 2 * (size_t)nPart * sizeof(int), stream);
        partition_kernel<<<(e + EPB - 1) / EPB, 512, 0, stream>>>(
            src, dst, curA, curB, streamA, streamB, e, nPart);
        convertB_kernel<<<nPart, 512, 0, stream>>>(curB, streamB, feat, featb, n);
        sortgather_kernel<<<nPart, 1024, 0, stream>>>(curA, streamA, feat, featb,
                                                      out, n);
    } else if (ws_size >= need_bf16) {
        int* cnt    = (int*)d_ws;
        int* outdeg = cnt + n;
        int* bucket = outdeg + n;
        unsigned short* featb = (unsigned short*)(bucket + (size_t)n * GC_CAP);

        zero_int_kernel<<<(2 * n + 255) / 256, 256, 0, stream>>>(cnt, 2 * n);
        bucket_hist_kernel<<<(e + 255) / 256, 256, 0, stream>>>(src, dst, cnt,
                                                                outdeg, bucket, e);
        int conv_threads = (n + 1) * 16;
        convert_kernel<<<(conv_threads + 255) / 256, 256, 0, stream>>>(
            feat, outdeg, featb, n);
        long long total = (long long)n * GC_D;
        gather_bf16_kernel<<<(int)((total + 255) / 256), 256, 0, stream>>>(
            feat, featb, bucket, cnt, out, n);
    }
}